// Round 12
// baseline (5222.558 us; speedup 1.0000x reference)
//
#include <hip/hip_runtime.h>
#include <math.h>

typedef __bf16 bf16;
typedef float f32x4 __attribute__((ext_vector_type(4)));
typedef bf16  bf16x4 __attribute__((ext_vector_type(4)));
typedef bf16  bf16x8 __attribute__((ext_vector_type(8)));

#define N_B  64
#define N_L  256
#define N_H  16
#define N_D  2048
#define N_HD 128
#define M_TOT (N_B * N_L)   // 16384

static __device__ __forceinline__ f32x4 shflx4(f32x4 v, int m) {
  f32x4 r;
  r[0] = __shfl_xor(v[0], m);
  r[1] = __shfl_xor(v[1], m);
  r[2] = __shfl_xor(v[2], m);
  r[3] = __shfl_xor(v[3], m);
  return r;
}
static __device__ __forceinline__ f32x4 max4(f32x4 a, f32x4 b) {
  f32x4 r;
  r[0] = fmaxf(a[0], b[0]); r[1] = fmaxf(a[1], b[1]);
  r[2] = fmaxf(a[2], b[2]); r[3] = fmaxf(a[3], b[3]);
  return r;
}

// ---------------- prep kernels ----------------
__global__ void k_cast_x(const float* __restrict__ x, bf16* __restrict__ xb, int n4) {
  int i = blockIdx.x * blockDim.x + threadIdx.x;
  int st = gridDim.x * blockDim.x;
  for (; i < n4; i += st) {
    float4 v = ((const float4*)x)[i];
    bf16x4 o;
    o[0] = (bf16)v.x; o[1] = (bf16)v.y; o[2] = (bf16)v.z; o[3] = (bf16)v.w;
    ((bf16x4*)xb)[i] = o;
  }
}

__global__ void k_transpose_w(const float* __restrict__ w, bf16* __restrict__ wt) {
  __shared__ float t[32][33];
  int n0 = blockIdx.x * 32, k0 = blockIdx.y * 32;
  t[threadIdx.y][threadIdx.x] = w[(size_t)(k0 + threadIdx.y) * N_D + n0 + threadIdx.x];
  __syncthreads();
  wt[(size_t)(n0 + threadIdx.y) * N_D + k0 + threadIdx.x] = (bf16)t[threadIdx.x][threadIdx.y];
}

__global__ void k_trig(float2* __restrict__ tab) {
  int idx = blockIdx.x * blockDim.x + threadIdx.x;
  if (idx < N_L * (N_HD / 2)) {
    int l = idx >> 6, i = idx & 63;
    float ang = (float)l * powf(10000.0f, -(float)(2 * i) / 128.0f);
    tab[idx].x = cosf(ang);
    tab[idx].y = sinf(ang);
  }
}

// ---------------- 256x256 MFMA GEMM, single-buffer LDS, 2 blocks/CU ----------------
// C[m][n] = sum_k A[m][k] * BT[n][k] + bias[n]
// r10/r11 conclusion: within a barrier-lockstep block, LDS reads and MFMA never
// overlap (r7: 5025 cy/tile = 2816 LDS + 2483 MFMA, zero overlap). Fix: keep
// r7's clean geometry (BK=64, 8-granule XOR swizzle: 0 conflicts; acc[8][4])
// but SINGLE-buffer the 64KB LDS -> 2 co-resident blocks/CU. The sibling
// block's MFMA covers this block's stage-drain and LDS bursts (m114 overlap).
// In-tile: counted-lgkm read-ahead, B-frag register reuse across q-phases.
// MODE 1: fp32 row-major. MODE 2: bf16 [b][h][d][l] (V^T). MODE 3: bf16 + RoPE.

#define GLOAD(GP, LP) __builtin_amdgcn_global_load_lds( \
    (const __attribute__((address_space(1))) void*)(GP), \
    (__attribute__((address_space(3))) void*)(LP), 16, 0, 0)
#define BARR()  __builtin_amdgcn_s_barrier()
#define SCHED() __builtin_amdgcn_sched_barrier(0)
#define PRIO1() __builtin_amdgcn_s_setprio(1)
#define PRIO0() __builtin_amdgcn_s_setprio(0)
#define WAITLGKM0() asm volatile("s_waitcnt lgkmcnt(0)" ::: "memory")
#define WAITLGKM4() asm volatile("s_waitcnt lgkmcnt(4)" ::: "memory")
#define WAITLGKM8() asm volatile("s_waitcnt lgkmcnt(8)" ::: "memory")
#define WAITVM0()   asm volatile("s_waitcnt vmcnt(0)" ::: "memory")

// Stage full 256x64 tile (4 chunks of 64 rows, 4 gloads/thread per matrix).
#define STAGE_A(KT) do { \
  _Pragma("unroll") for (int c_ = 0; c_ < 4; ++c_) \
    GLOAD(Ag + (size_t)srcA[c_] + (size_t)(KT) * 64, As + ldsOff[c_]); \
} while (0)
#define STAGE_B(KT) do { \
  _Pragma("unroll") for (int c_ = 0; c_ < 4; ++c_) \
    GLOAD(Bg + (size_t)srcB[c_] + (size_t)(KT) * 64, Bs + ldsOff[c_]); \
} while (0)

// A quadrant Q (4 m-frags x 2 kk = 8 x ds_read_b128)
#define RD_AQ(DST, Q) do { \
  _Pragma("unroll") for (int i_ = 0; i_ < 4; ++i_) { \
    const int R_ = wm * 128 + ((Q) * 4 + i_) * 16 + lr; \
    _Pragma("unroll") for (int kk_ = 0; kk_ < 2; ++kk_) \
      DST[i_ * 2 + kk_] = *(const bf16x8*)&As[R_ * 64 + (((kk_ * 4 + lg) ^ (R_ & 7)) << 3)]; \
  } \
} while (0)
// B half H (2 n-frags x 2 kk = 4 x ds_read_b128)
#define RD_BH(DST, H) do { \
  _Pragma("unroll") for (int j_ = 0; j_ < 2; ++j_) { \
    const int R_ = wn * 64 + ((H) * 2 + j_) * 16 + lr; \
    _Pragma("unroll") for (int kk_ = 0; kk_ < 2; ++kk_) \
      DST[j_ * 2 + kk_] = *(const bf16x8*)&Bs[R_ * 64 + (((kk_ * 4 + lg) ^ (R_ & 7)) << 3)]; \
  } \
} while (0)

// 16 MFMAs: quadrant Q x half H (4i x 2j x 2kk)
#define MFMA16(AB, BB, Q, H) do { \
  _Pragma("unroll") for (int i_ = 0; i_ < 4; ++i_) \
  _Pragma("unroll") for (int j_ = 0; j_ < 2; ++j_) \
  _Pragma("unroll") for (int kk_ = 0; kk_ < 2; ++kk_) \
    acc[(Q) * 4 + i_][(H) * 2 + j_] = __builtin_amdgcn_mfma_f32_16x16x32_bf16( \
        AB[i_ * 2 + kk_], BB[j_ * 2 + kk_], acc[(Q) * 4 + i_][(H) * 2 + j_], 0, 0, 0); \
} while (0)

template<int MODE>
__global__ __launch_bounds__(512, 4) void k_gemm256(
    const bf16* __restrict__ A, const bf16* __restrict__ BT,
    const float* __restrict__ bias, void* __restrict__ dstv,
    const float2* __restrict__ tab)
{
  __shared__ bf16 As[256 * 64];   // 32 KB
  __shared__ bf16 Bs[256 * 64];   // 32 KB  (64 KB total -> 2 blocks/CU)
  const int bid = blockIdx.x;
  // XCD-aware (r7-proven): XCD (bid&7) owns an 8-tile m-strip, sweeps bn fast.
  const int xcd = bid & 7, idx = bid >> 3;
  const int bm = xcd * 8 + (idx >> 3), bn = idx & 7;
  const int m0 = bm * 256, n0 = bn * 256;
  const int tid = threadIdx.x;
  const int wave = tid >> 6, lane = tid & 63;
  const int wm = wave >> 2, wn = wave & 3;
  const int lr = lane & 15, lg = lane >> 4;
  const bf16* __restrict__ Ag = A;
  const bf16* __restrict__ Bg = BT;

  // staging addresses: thread covers granule (tid&7) of row (c*64 + tid>>3)
  int srcA[4], srcB[4], ldsOff[4];
  {
    const int g7 = tid & 7, rr = tid >> 3;
    const int swz = (g7 ^ (rr & 7)) << 3;
#pragma unroll
    for (int c = 0; c < 4; ++c) {
      srcA[c] = (m0 + c * 64 + rr) * N_D + swz;
      srcB[c] = (n0 + c * 64 + rr) * N_D + swz;
      ldsOff[c] = (c * 64 + wave * 8) * 64;
    }
  }

  f32x4 acc[8][4];
#pragma unroll
  for (int i = 0; i < 8; ++i)
#pragma unroll
    for (int j = 0; j < 4; ++j)
      acc[i][j] = (f32x4){0.f, 0.f, 0.f, 0.f};

  bf16x8 A0b[8], A1b[8], B0b[4], B1b[4];

#pragma unroll 1
  for (int t = 0; t < N_D / 64; ++t) {
    // ---- stage tile t (prev tile's reads all lgkm-drained before last barrier)
    STAGE_A(t); STAGE_B(t);
    WAITVM0(); BARR();
    // ---- in-tile compute with counted-lgkm read-ahead ----
    // issue order: Bh0(4), Aq0(8), Bh1(4) -> 16 outstanding
    RD_BH(B0b, 0); RD_AQ(A0b, 0); RD_BH(B1b, 1);
    WAITLGKM4(); SCHED();                 // drains Bh0 + Aq0 (12 oldest)
    PRIO1(); MFMA16(A0b, B0b, 0, 0); PRIO0();
    RD_AQ(A1b, 1);                        // +8 -> 12 outstanding
    WAITLGKM8(); SCHED();                 // drains Bh1 (oldest 4)
    PRIO1(); MFMA16(A0b, B1b, 0, 1); PRIO0();
    WAITLGKM0(); SCHED();                 // drains Aq1
    PRIO1(); MFMA16(A1b, B0b, 1, 0); MFMA16(A1b, B1b, 1, 1); PRIO0();
    BARR();                               // all waves' LDS reads retired
  }

  // ---- epilogue ----
#pragma unroll
  for (int i = 0; i < 8; ++i) {
#pragma unroll
    for (int r = 0; r < 4; ++r) {
      const int m = m0 + wm * 128 + i * 16 + lg * 4 + r;
#pragma unroll
      for (int j = 0; j < 4; ++j) {
        const int n = n0 + wn * 64 + j * 16 + lr;
        float v = acc[i][j][r] + bias[n];
        if (MODE == 3) {
          // fused RoPE: lanes lr, lr^1 hold adjacent d at the same row m
          float partner = __shfl_xor(v, 1);
          const int d = n & 127, l = m & 255;
          float2 cs = tab[(l << 6) | (d >> 1)];
          v = (d & 1) ? (v * cs.x + partner * cs.y) : (v * cs.x - partner * cs.y);
        }
        if (MODE == 0 || MODE == 3) {
          bf16* dst = (bf16*)dstv;
          const int b = m >> 8, l = m & 255;
          const int h = n >> 7, d = n & 127;
          dst[(((size_t)b * N_H + h) * N_L + l) * N_HD + d] = (bf16)v;
        } else if (MODE == 2) {
          bf16* dst = (bf16*)dstv;
          const int b = m >> 8, l = m & 255;
          const int h = n >> 7, d = n & 127;
          dst[(((size_t)b * N_H + h) * N_HD + d) * N_L + l] = (bf16)v;
        } else {
          float* dst = (float*)dstv;
          dst[(size_t)m * N_D + n] = v;
        }
      }
    }
  }
}

// ---------------- MFMA flash attention: one block per (b,h), 8 waves ----------------
// Q,K in [b][h][l][d] (RoPE applied). Vt in [b][h][d][l]. O to [b][l][h][d].
__global__ __launch_bounds__(512) void k_attn_mfma(
    const bf16* __restrict__ Q, const bf16* __restrict__ K,
    const bf16* __restrict__ Vt, bf16* __restrict__ O)
{
  __shared__ bf16 Kl[N_L * N_HD];   // 64KB; row j = 256B = 16 granules; granule g holds src granule g^(j&7)
  __shared__ bf16 Pl[8][16][56];    // per-wave P staging; 112B row stride

  const int bh = blockIdx.x;
  const int b = bh >> 4, h = bh & 15;
  const int tid = threadIdx.x;
  const int wave = tid >> 6, lane = tid & 63;
  const int c = lane & 15, g8 = lane >> 4;

  const bf16* Qg = Q + (size_t)bh * (N_L * N_HD);
  const bf16* Kg = K + (size_t)bh * (N_L * N_HD);
  const bf16* Vg = Vt + (size_t)bh * (N_L * N_HD);

#pragma unroll
  for (int t = 0; t < 8; ++t) {
    int idx = tid + 512 * t;            // 16B-granule index, 4096 total
    int row = idx >> 4, g = idx & 15;
    const bf16* src = Kg + row * N_HD + ((g ^ (row & 7)) << 3);
    __builtin_amdgcn_global_load_lds(
        (const __attribute__((address_space(1))) void*)src,
        (__attribute__((address_space(3))) void*)(Kl + (size_t)wave * 512 + (size_t)t * 4096),
        16, 0, 0);
  }
  __syncthreads();

  const float scale = 0.08838834764831843f;  // 1/sqrt(128)

  for (int half = 0; half < 2; ++half) {
    const int qb = half ? (15 - wave) : wave;
    const int q0 = qb * 16;

    bf16x8 qf[4];
#pragma unroll
    for (int dk = 0; dk < 4; ++dk)
      qf[dk] = *(const bf16x8*)(Qg + (size_t)(q0 + c) * N_HD + dk * 32 + g8 * 8);

    f32x4 o[8];
#pragma unroll
    for (int dj = 0; dj < 8; ++dj) o[dj] = (f32x4){0.f, 0.f, 0.f, 0.f};
    f32x4 mrow = (f32x4){-INFINITY, -INFINITY, -INFINITY, -INFINITY};
    f32x4 lrow = (f32x4){0.f, 0.f, 0.f, 0.f};

    const int nsteps = ((q0 + 15) >> 5) + 1;
    for (int js = 0; js < nsteps; ++js) {
      const int j0 = js * 32;

      bf16x8 vf[4];
#pragma unroll
      for (int dj = 0; dj < 4; ++dj)
        vf[dj] = *(const bf16x8*)(Vg + (size_t)(dj * 16 + c) * N_L + j0 + g8 * 8);

      f32x4 s0 = (f32x4){0.f, 0.f, 0.f, 0.f};
      f32x4 s1 = (f32x4){0.f, 0.f, 0.f, 0.f};
#pragma unroll
      for (int dk = 0; dk < 4; ++dk) {
        int row0 = j0 + c;
        int row1 = j0 + 16 + c;
        bf16x8 kf0 = *(const bf16x8*)(Kl + row0 * N_HD + (((dk * 4 + g8) ^ (row0 & 7)) << 3));
        bf16x8 kf1 = *(const bf16x8*)(Kl + row1 * N_HD + (((dk * 4 + g8) ^ (row1 & 7)) << 3));
        s0 = __builtin_amdgcn_mfma_f32_16x16x32_bf16(qf[dk], kf0, s0, 0, 0, 0);
        s1 = __builtin_amdgcn_mfma_f32_16x16x32_bf16(qf[dk], kf1, s1, 0, 0, 0);
      }

      // mask whenever the tile touches the upper triangle: j0+31 > q0
      f32x4 sv0, sv1;
#pragma unroll
      for (int r = 0; r < 4; ++r) { sv0[r] = s0[r] * scale; sv1[r] = s1[r] * scale; }
      if (j0 + 31 > q0) {
#pragma unroll
        for (int r = 0; r < 4; ++r) {
          int q = q0 + g8 * 4 + r;
          if (j0 + c > q)      sv0[r] = -INFINITY;
          if (j0 + 16 + c > q) sv1[r] = -INFINITY;
        }
      }

      f32x4 mx = max4(sv0, sv1);
      mx = max4(mx, shflx4(mx, 1));
      mx = max4(mx, shflx4(mx, 2));
      mx = max4(mx, shflx4(mx, 4));
      mx = max4(mx, shflx4(mx, 8));
      f32x4 mnew = max4(mrow, mx);
      f32x4 resc, p0, p1;
#pragma unroll
      for (int r = 0; r < 4; ++r) {
        resc[r] = __expf(mrow[r] - mnew[r]);
        p0[r] = __expf(sv0[r] - mnew[r]);
        p1[r] = __expf(sv1[r] - mnew[r]);
      }
      f32x4 rsum = p0 + p1;
      rsum += shflx4(rsum, 1);
      rsum += shflx4(rsum, 2);
      rsum += shflx4(rsum, 4);
      rsum += shflx4(rsum, 8);
      lrow = lrow * resc + rsum;
      mrow = mnew;
#pragma unroll
      for (int dj = 0; dj < 8; ++dj) o[dj] *= resc;

#pragma unroll
      for (int r = 0; r < 4; ++r) {
        Pl[wave][g8 * 4 + r][c] = (bf16)p0[r];
        Pl[wave][g8 * 4 + r][16 + c] = (bf16)p1[r];
      }
      bf16x8 pf = *(const bf16x8*)&Pl[wave][c][g8 * 8];

      bf16x8 vg[4];
#pragma unroll
      for (int dj = 0; dj < 4; ++dj)
        vg[dj] = *(const bf16x8*)(Vg + (size_t)((dj + 4) * 16 + c) * N_L + j0 + g8 * 8);

#pragma unroll
      for (int dj = 0; dj < 4; ++dj)
        o[dj] = __builtin_amdgcn_mfma_f32_16x16x32_bf16(pf, vf[dj], o[dj], 0, 0, 0);
#pragma unroll
      for (int dj = 0; dj < 4; ++dj)
        o[dj + 4] = __builtin_amdgcn_mfma_f32_16x16x32_bf16(pf, vg[dj], o[dj + 4], 0, 0, 0);
    }

    f32x4 inv;
#pragma unroll
    for (int r = 0; r < 4; ++r) inv[r] = 1.0f / lrow[r];
#pragma unroll
    for (int dj = 0; dj < 8; ++dj) {
      f32x4 ov = o[dj] * inv;
#pragma unroll
      for (int r = 0; r < 4; ++r) {
        int q = q0 + g8 * 4 + r;
        int d = dj * 16 + c;
        O[(((size_t)b * N_L + q) * N_H + h) * N_HD + d] = (bf16)ov[r];
      }
    }
  }
}

// ---------------- launch ----------------
extern "C" void kernel_launch(void* const* d_in, const int* in_sizes, int n_in,
                              void* d_out, int out_size, void* d_ws, size_t ws_size,
                              hipStream_t stream) {
  const float* x  = (const float*)d_in[0];
  const float* wq = (const float*)d_in[1];
  const float* bq = (const float*)d_in[2];
  const float* wk = (const float*)d_in[3];
  const float* bk = (const float*)d_in[4];
  const float* wv = (const float*)d_in[5];
  const float* bv = (const float*)d_in[6];
  const float* wo = (const float*)d_in[7];
  const float* bo = (const float*)d_in[8];

  char* ws = (char*)d_ws;
  const size_t WSZ = (size_t)N_D * N_D * sizeof(bf16);    // 8 MB per transposed weight
  const size_t XSZ = (size_t)M_TOT * N_D * sizeof(bf16);  // 64 MB per activation tensor
  bf16* wqT = (bf16*)(ws);
  bf16* wkT = (bf16*)(ws + WSZ);
  bf16* wvT = (bf16*)(ws + 2 * WSZ);
  bf16* woT = (bf16*)(ws + 3 * WSZ);
  bf16* xb  = (bf16*)(ws + 4 * WSZ);
  bf16* Qb  = (bf16*)(ws + 4 * WSZ + XSZ);
  bf16* Kb  = (bf16*)(ws + 4 * WSZ + 2 * XSZ);
  bf16* Vb  = (bf16*)(ws + 4 * WSZ + 3 * XSZ);  // holds V^T: [b][h][d][l]
  bf16* Ob  = (bf16*)(ws + 4 * WSZ + 4 * XSZ);
  float2* tab = (float2*)(ws + 4 * WSZ + 5 * XSZ);

  k_cast_x<<<2048, 256, 0, stream>>>(x, xb, M_TOT * N_D / 4);
  dim3 tb(32, 32), tg(64, 64);
  k_transpose_w<<<tg, tb, 0, stream>>>(wq, wqT);
  k_transpose_w<<<tg, tb, 0, stream>>>(wk, wkT);
  k_transpose_w<<<tg, tb, 0, stream>>>(wv, wvT);
  k_transpose_w<<<tg, tb, 0, stream>>>(wo, woT);
  k_trig<<<64, 256, 0, stream>>>(tab);

  const int grid = (M_TOT / 256) * (N_D / 256);  // 512 = 2 blocks/CU
  k_gemm256<3><<<grid, 512, 0, stream>>>(xb, wqT, bq, Qb, tab);   // Q proj + RoPE
  k_gemm256<3><<<grid, 512, 0, stream>>>(xb, wkT, bk, Kb, tab);   // K proj + RoPE
  k_gemm256<2><<<grid, 512, 0, stream>>>(xb, wvT, bv, Vb, tab);   // V proj, transposed

  k_attn_mfma<<<1024, 512, 0, stream>>>(Qb, Kb, Vb, Ob);
  k_gemm256<1><<<grid, 512, 0, stream>>>(Ob, woT, bo, d_out, tab);
}

// Round 14
// 671.161 us; speedup vs baseline: 7.7814x; 7.7814x over previous
//
#include <hip/hip_runtime.h>
#include <math.h>

typedef __bf16 bf16;
typedef float f32x4 __attribute__((ext_vector_type(4)));
typedef bf16  bf16x4 __attribute__((ext_vector_type(4)));
typedef bf16  bf16x8 __attribute__((ext_vector_type(8)));

#define N_B  64
#define N_L  256
#define N_H  16
#define N_D  2048
#define N_HD 128
#define M_TOT (N_B * N_L)   // 16384

static __device__ __forceinline__ f32x4 shflx4(f32x4 v, int m) {
  f32x4 r;
  r[0] = __shfl_xor(v[0], m);
  r[1] = __shfl_xor(v[1], m);
  r[2] = __shfl_xor(v[2], m);
  r[3] = __shfl_xor(v[3], m);
  return r;
}
static __device__ __forceinline__ f32x4 max4(f32x4 a, f32x4 b) {
  f32x4 r;
  r[0] = fmaxf(a[0], b[0]); r[1] = fmaxf(a[1], b[1]);
  r[2] = fmaxf(a[2], b[2]); r[3] = fmaxf(a[3], b[3]);
  return r;
}

// ---------------- prep kernels ----------------
__global__ void k_cast_x(const float* __restrict__ x, bf16* __restrict__ xb, int n4) {
  int i = blockIdx.x * blockDim.x + threadIdx.x;
  int st = gridDim.x * blockDim.x;
  for (; i < n4; i += st) {
    float4 v = ((const float4*)x)[i];
    bf16x4 o;
    o[0] = (bf16)v.x; o[1] = (bf16)v.y; o[2] = (bf16)v.z; o[3] = (bf16)v.w;
    ((bf16x4*)xb)[i] = o;
  }
}

// All four weight transposes in one launch (blockIdx.z selects the tensor).
__global__ void k_transpose_w4(const float* __restrict__ w0, const float* __restrict__ w1,
                               const float* __restrict__ w2, const float* __restrict__ w3,
                               bf16* __restrict__ t0, bf16* __restrict__ t1,
                               bf16* __restrict__ t2, bf16* __restrict__ t3) {
  __shared__ float t[32][33];
  const float* w; bf16* wt;
  switch (blockIdx.z) {
    case 0:  w = w0; wt = t0; break;
    case 1:  w = w1; wt = t1; break;
    case 2:  w = w2; wt = t2; break;
    default: w = w3; wt = t3; break;
  }
  int n0 = blockIdx.x * 32, k0 = blockIdx.y * 32;
  t[threadIdx.y][threadIdx.x] = w[(size_t)(k0 + threadIdx.y) * N_D + n0 + threadIdx.x];
  __syncthreads();
  wt[(size_t)(n0 + threadIdx.y) * N_D + k0 + threadIdx.x] = (bf16)t[threadIdx.x][threadIdx.y];
}

__global__ void k_trig(float2* __restrict__ tab) {
  int idx = blockIdx.x * blockDim.x + threadIdx.x;
  if (idx < N_L * (N_HD / 2)) {
    int l = idx >> 6, i = idx & 63;
    float ang = (float)l * powf(10000.0f, -(float)(2 * i) / 128.0f);
    tab[idx].x = cosf(ang);
    tab[idx].y = sinf(ang);
  }
}

// ---------------- 256x256 read-ahead MFMA GEMM (race-fixed vm ledger) ----------------
// C[m][n] = sum_k A[m][k] * BT[n][k] + bias[n]
// 8 waves (2M x 4N), per-wave 128x64, BK=64, dbuf 128KB LDS.
// CROSS-WAVE RULE (r13 lesson): vmcnt is per-wave; data staged by wave V and
// read by wave W needs V's drain BEFORE a barrier BEFORE W's read. r7 placed
// vm waits at phase STARTS (same phase as the consuming reads -> latent race,
// timing-dependent). Fixed: vm6 at END of P0 (retires A1(T), read in P1),
// vm4 at END of P2 (retires A0(T+1), B0(T+1), B1(T+1); read in P3/next-P0).
// Steady-state queue/tile: 6 ->P0+2,vm6-> 6 ->P1+2-> 8 ->P2+2,vm4-> 4 ->P3+2-> 6.
// MODE 1: fp32 row-major. MODE 2: bf16 [b][h][d][l] (V^T). MODE 3: bf16 + RoPE.

#define GLOAD(GP, LP) __builtin_amdgcn_global_load_lds( \
    (const __attribute__((address_space(1))) void*)(GP), \
    (__attribute__((address_space(3))) void*)(LP), 16, 0, 0)
#define BARR()  __builtin_amdgcn_s_barrier()
#define SCHED() __builtin_amdgcn_sched_barrier(0)
#define PRIO1() __builtin_amdgcn_s_setprio(1)
#define PRIO0() __builtin_amdgcn_s_setprio(0)
#define WAITLGKM4() asm volatile("s_waitcnt lgkmcnt(4)" ::: "memory")
#define WAITLGKM8() asm volatile("s_waitcnt lgkmcnt(8)" ::: "memory")
#define WAITVM4()   asm volatile("s_waitcnt vmcnt(4)" ::: "memory")
#define WAITVM6()   asm volatile("s_waitcnt vmcnt(6)" ::: "memory")

// KT masked &31 so tail tiles stage in-range (never-read) data.
#define STAGE_A(X, KT, BUF) do { \
  GLOAD(Ag + (size_t)srcOffA[0][X] + (size_t)((KT) & 31) * 64, (BUF) + ldsOffA[0][X]); \
  GLOAD(Ag + (size_t)srcOffA[1][X] + (size_t)((KT) & 31) * 64, (BUF) + ldsOffA[1][X]); \
} while (0)
#define STAGE_B(X, KT, BUF) do { \
  GLOAD(Bg + (size_t)srcOffB[0][X] + (size_t)((KT) & 31) * 64, (BUF) + ldsOffB[0][X]); \
  GLOAD(Bg + (size_t)srcOffB[1][X] + (size_t)((KT) & 31) * 64, (BUF) + ldsOffB[1][X]); \
} while (0)

// A chunk (m-half MH, k-slice KK): 4 x ds_read_b128
#define RD_A(DST, MH, KK, BUF) do { \
  _Pragma("unroll") for (int i_ = 0; i_ < 4; ++i_) { \
    const int R_ = wm * 128 + (MH) * 64 + i_ * 16 + lr; \
    DST[i_] = *(const bf16x8*)&(BUF)[R_ * 64 + ((((KK) * 4 + lg) ^ (R_ & 7)) << 3)]; \
  } \
} while (0)
// B chunk (k-slice KK): 4 x ds_read_b128 (all 4 n-frags of the wave)
#define RD_B(DST, KK, BUF) do { \
  _Pragma("unroll") for (int j_ = 0; j_ < 4; ++j_) { \
    const int R_ = wn * 64 + j_ * 16 + lr; \
    DST[j_] = *(const bf16x8*)&(BUF)[R_ * 64 + ((((KK) * 4 + lg) ^ (R_ & 7)) << 3)]; \
  } \
} while (0)

// 16 independent MFMAs: chunk (MH, k) x all 4 n-frags
#define MFMA16(AB, BB, MH) do { \
  _Pragma("unroll") for (int i_ = 0; i_ < 4; ++i_) \
  _Pragma("unroll") for (int j_ = 0; j_ < 4; ++j_) \
    acc[(MH) * 4 + i_][j_] = __builtin_amdgcn_mfma_f32_16x16x32_bf16( \
        AB[i_], BB[j_], acc[(MH) * 4 + i_], [j_] + 0, 0, 0, 0); \
} while (0)
#undef MFMA16
#define MFMA16(AB, BB, MH) do { \
  _Pragma("unroll") for (int i_ = 0; i_ < 4; ++i_) \
  _Pragma("unroll") for (int j_ = 0; j_ < 4; ++j_) \
    acc[(MH) * 4 + i_][j_] = __builtin_amdgcn_mfma_f32_16x16x32_bf16( \
        AB[i_], BB[j_], acc[(MH) * 4 + i_][j_], 0, 0, 0); \
} while (0)

// Chunk order c0=(m0,k0) c1=(m0,k1) c2=(m1,k0) c3=(m1,k1).
// Banks: c0->A0b, c1->A1b, c2->A0b, c3->A1b; B0b=k0, B1b=k1.
// Phase p MFMAs chunk p using ds_reads issued at phase p-1 (counted lgkm).
// Stage slots: B1(t+1)@P0, A1(t+1)@P1, A0(t+2)@P2, B0(t+2)@P3.
// vm waits at END of P0 (vm6) and END of P2 (vm4), always BEFORE the barrier.
#define TILE(T, CURA, CURB, OTHA, OTHB) do { \
  /* P0 */ \
  STAGE_B(1, (T) + 1, OTHB); \
  RD_A(A1b, 0, 1, CURA); RD_B(B1b, 1, CURB); \
  SCHED(); WAITLGKM8(); SCHED(); \
  PRIO1(); MFMA16(A0b, B0b, 0); PRIO0(); \
  SCHED(); WAITVM6(); BARR(); \
  /* P1 */ \
  STAGE_A(1, (T) + 1, OTHA); \
  RD_A(A0b, 1, 0, CURA); \
  SCHED(); WAITLGKM4(); SCHED(); \
  PRIO1(); MFMA16(A1b, B1b, 0); PRIO0(); \
  SCHED(); BARR(); \
  /* P2 */ \
  STAGE_A(0, (T) + 2, CURA); \
  RD_A(A1b, 1, 1, CURA); \
  SCHED(); WAITLGKM4(); SCHED(); \
  PRIO1(); MFMA16(A0b, B0b, 1); PRIO0(); \
  SCHED(); WAITVM4(); BARR(); \
  /* P3 */ \
  STAGE_B(0, (T) + 2, CURB); \
  RD_A(A0b, 0, 0, OTHA); RD_B(B0b, 0, OTHB); \
  SCHED(); WAITLGKM8(); SCHED(); \
  PRIO1(); MFMA16(A1b, B1b, 1); PRIO0(); \
  SCHED(); BARR(); \
} while (0)

template<int MODE>
__global__ __launch_bounds__(512, 2) void k_gemm256(
    const bf16* __restrict__ A, const bf16* __restrict__ BT,
    const float* __restrict__ bias, void* __restrict__ dstv,
    const float2* __restrict__ tab)
{
  __shared__ bf16 lds[2][2][256 * 64];   // [buf][A=0/B=1], 128 KB total
  const int bid = blockIdx.x;
  // XCD-aware mapping: XCD (bid&7) owns an 8-tile m-strip, sweeps bn fast.
  const int xcd = bid & 7, idx = bid >> 3;
  const int bm = xcd * 8 + (idx >> 3), bn = idx & 7;
  const int m0 = bm * 256, n0 = bn * 256;
  const int tid = threadIdx.x;
  const int wave = tid >> 6, lane = tid & 63;
  const int wm = wave >> 2, wn = wave & 3;
  const int lr = lane & 15, lg = lane >> 4;
  const bf16* __restrict__ Ag = A;
  const bf16* __restrict__ Bg = BT;

  // staging address precompute
  int srcOffA[2][2], srcOffB[2][2], ldsOffA[2][2], ldsOffB[2][2];
  {
    const int g7 = tid & 7;
#pragma unroll
    for (int u = 0; u < 2; ++u) {
      const int rl  = u * 64 + (tid >> 3);
      const int rl0 = u * 64 + wave * 8;
#pragma unroll
      for (int X = 0; X < 2; ++X) {
        const int rA  = ((rl >> 6) << 7)  | (X << 6) | (rl & 63);
        const int rA0 = ((rl0 >> 6) << 7) | (X << 6) | (rl0 & 63);
        srcOffA[u][X] = (m0 + rA) * N_D + ((g7 ^ (rA & 7)) << 3);
        ldsOffA[u][X] = rA0 * 64;
        const int rB  = ((rl >> 5) << 6)  | (X << 5) | (rl & 31);
        const int rB0 = ((rl0 >> 5) << 6) | (X << 5) | (rl0 & 31);
        srcOffB[u][X] = (n0 + rB) * N_D + ((g7 ^ (rB & 7)) << 3);
        ldsOffB[u][X] = rB0 * 64;
      }
    }
  }

  bf16* bufA0 = &lds[0][0][0];
  bf16* bufB0 = &lds[0][1][0];
  bf16* bufA1 = &lds[1][0][0];
  bf16* bufB1 = &lds[1][1][0];

  f32x4 acc[8][4];
#pragma unroll
  for (int i = 0; i < 8; ++i)
#pragma unroll
    for (int j = 0; j < 4; ++j)
      acc[i][j] = (f32x4){0.f, 0.f, 0.f, 0.f};

  bf16x8 A0b[4], A1b[4], B0b[4], B1b[4];

  // prologue: tile0 fully (8) + tile1 A0,B0 (4); drain tile0 BEFORE barrier.
  STAGE_A(0, 0, bufA0); STAGE_B(0, 0, bufB0);
  STAGE_B(1, 0, bufB0); STAGE_A(1, 0, bufA0);
  STAGE_A(0, 1, bufA1); STAGE_B(0, 1, bufB1);
  SCHED(); WAITVM4(); BARR(); SCHED();
  RD_A(A0b, 0, 0, bufA0); RD_B(B0b, 0, bufB0);
  SCHED();

#pragma unroll 1
  for (int t = 0; t < N_D / 64; t += 2) {
    TILE(t,     bufA0, bufB0, bufA1, bufB1);
    TILE(t + 1, bufA1, bufB1, bufA0, bufB0);
  }

  // ---- epilogue ----
#pragma unroll
  for (int i = 0; i < 8; ++i) {
#pragma unroll
    for (int r = 0; r < 4; ++r) {
      const int m = m0 + wm * 128 + i * 16 + lg * 4 + r;
#pragma unroll
      for (int j = 0; j < 4; ++j) {
        const int n = n0 + wn * 64 + j * 16 + lr;
        float v = acc[i][j][r] + bias[n];
        if (MODE == 3) {
          // fused RoPE: lanes lr, lr^1 hold adjacent d at the same row m
          float partner = __shfl_xor(v, 1);
          const int d = n & 127, l = m & 255;
          float2 cs = tab[(l << 6) | (d >> 1)];
          v = (d & 1) ? (v * cs.x + partner * cs.y) : (v * cs.x - partner * cs.y);
        }
        if (MODE == 0 || MODE == 3) {
          bf16* dst = (bf16*)dstv;
          const int b = m >> 8, l = m & 255;
          const int h = n >> 7, d = n & 127;
          dst[(((size_t)b * N_H + h) * N_L + l) * N_HD + d] = (bf16)v;
        } else if (MODE == 2) {
          bf16* dst = (bf16*)dstv;
          const int b = m >> 8, l = m & 255;
          const int h = n >> 7, d = n & 127;
          dst[(((size_t)b * N_H + h) * N_HD + d) * N_L + l] = (bf16)v;
        } else {
          float* dst = (float*)dstv;
          dst[(size_t)m * N_D + n] = v;
        }
      }
    }
  }
}

// ---------------- MFMA flash attention: one block per (b,h), 8 waves ----------------
// Q,K in [b][h][l][d] (RoPE applied). Vt in [b][h][d][l]. O to [b][l][h][d].
__global__ __launch_bounds__(512) void k_attn_mfma(
    const bf16* __restrict__ Q, const bf16* __restrict__ K,
    const bf16* __restrict__ Vt, bf16* __restrict__ O)
{
  __shared__ bf16 Kl[N_L * N_HD];   // 64KB; row j = 256B = 16 granules; granule g holds src granule g^(j&7)
  __shared__ bf16 Pl[8][16][56];    // per-wave P staging; 112B row stride

  const int bh = blockIdx.x;
  const int b = bh >> 4, h = bh & 15;
  const int tid = threadIdx.x;
  const int wave = tid >> 6, lane = tid & 63;
  const int c = lane & 15, g8 = lane >> 4;

  const bf16* Qg = Q + (size_t)bh * (N_L * N_HD);
  const bf16* Kg = K + (size_t)bh * (N_L * N_HD);
  const bf16* Vg = Vt + (size_t)bh * (N_L * N_HD);

#pragma unroll
  for (int t = 0; t < 8; ++t) {
    int idx = tid + 512 * t;            // 16B-granule index, 4096 total
    int row = idx >> 4, g = idx & 15;
    const bf16* src = Kg + row * N_HD + ((g ^ (row & 7)) << 3);
    __builtin_amdgcn_global_load_lds(
        (const __attribute__((address_space(1))) void*)src,
        (__attribute__((address_space(3))) void*)(Kl + (size_t)wave * 512 + (size_t)t * 4096),
        16, 0, 0);
  }
  __syncthreads();

  const float scale = 0.08838834764831843f;  // 1/sqrt(128)

  for (int half = 0; half < 2; ++half) {
    const int qb = half ? (15 - wave) : wave;
    const int q0 = qb * 16;

    bf16x8 qf[4];
#pragma unroll
    for (int dk = 0; dk < 4; ++dk)
      qf[dk] = *(const bf16x8*)(Qg + (size_t)(q0 + c) * N_HD + dk * 32 + g8 * 8);

    f32x4 o[8];
#pragma unroll
    for (int dj = 0; dj < 8; ++dj) o[dj] = (f32x4){0.f, 0.f, 0.f, 0.f};
    f32x4 mrow = (f32x4){-INFINITY, -INFINITY, -INFINITY, -INFINITY};
    f32x4 lrow = (f32x4){0.f, 0.f, 0.f, 0.f};

    const int nsteps = ((q0 + 15) >> 5) + 1;
    for (int js = 0; js < nsteps; ++js) {
      const int j0 = js * 32;

      bf16x8 vf[4];
#pragma unroll
      for (int dj = 0; dj < 4; ++dj)
        vf[dj] = *(const bf16x8*)(Vg + (size_t)(dj * 16 + c) * N_L + j0 + g8 * 8);

      f32x4 s0 = (f32x4){0.f, 0.f, 0.f, 0.f};
      f32x4 s1 = (f32x4){0.f, 0.f, 0.f, 0.f};
#pragma unroll
      for (int dk = 0; dk < 4; ++dk) {
        int row0 = j0 + c;
        int row1 = j0 + 16 + c;
        bf16x8 kf0 = *(const bf16x8*)(Kl + row0 * N_HD + (((dk * 4 + g8) ^ (row0 & 7)) << 3));
        bf16x8 kf1 = *(const bf16x8*)(Kl + row1 * N_HD + (((dk * 4 + g8) ^ (row1 & 7)) << 3));
        s0 = __builtin_amdgcn_mfma_f32_16x16x32_bf16(qf[dk], kf0, s0, 0, 0, 0);
        s1 = __builtin_amdgcn_mfma_f32_16x16x32_bf16(qf[dk], kf1, s1, 0, 0, 0);
      }

      // mask whenever the tile touches the upper triangle: j0+31 > q0
      f32x4 sv0, sv1;
#pragma unroll
      for (int r = 0; r < 4; ++r) { sv0[r] = s0[r] * scale; sv1[r] = s1[r] * scale; }
      if (j0 + 31 > q0) {
#pragma unroll
        for (int r = 0; r < 4; ++r) {
          int q = q0 + g8 * 4 + r;
          if (j0 + c > q)      sv0[r] = -INFINITY;
          if (j0 + 16 + c > q) sv1[r] = -INFINITY;
        }
      }

      f32x4 mx = max4(sv0, sv1);
      mx = max4(mx, shflx4(mx, 1));
      mx = max4(mx, shflx4(mx, 2));
      mx = max4(mx, shflx4(mx, 4));
      mx = max4(mx, shflx4(mx, 8));
      f32x4 mnew = max4(mrow, mx);
      f32x4 resc, p0, p1;
#pragma unroll
      for (int r = 0; r < 4; ++r) {
        resc[r] = __expf(mrow[r] - mnew[r]);
        p0[r] = __expf(sv0[r] - mnew[r]);
        p1[r] = __expf(sv1[r] - mnew[r]);
      }
      f32x4 rsum = p0 + p1;
      rsum += shflx4(rsum, 1);
      rsum += shflx4(rsum, 2);
      rsum += shflx4(rsum, 4);
      rsum += shflx4(rsum, 8);
      lrow = lrow * resc + rsum;
      mrow = mnew;
#pragma unroll
      for (int dj = 0; dj < 8; ++dj) o[dj] *= resc;

#pragma unroll
      for (int r = 0; r < 4; ++r) {
        Pl[wave][g8 * 4 + r][c] = (bf16)p0[r];
        Pl[wave][g8 * 4 + r][16 + c] = (bf16)p1[r];
      }
      bf16x8 pf = *(const bf16x8*)&Pl[wave][c][g8 * 8];

      bf16x8 vg[4];
#pragma unroll
      for (int dj = 0; dj < 4; ++dj)
        vg[dj] = *(const bf16x8*)(Vg + (size_t)((dj + 4) * 16 + c) * N_L + j0 + g8 * 8);

#pragma unroll
      for (int dj = 0; dj < 4; ++dj)
        o[dj] = __builtin_amdgcn_mfma_f32_16x16x32_bf16(pf, vf[dj], o[dj], 0, 0, 0);
#pragma unroll
      for (int dj = 0; dj < 4; ++dj)
        o[dj + 4] = __builtin_amdgcn_mfma_f32_16x16x32_bf16(pf, vg[dj], o[dj + 4], 0, 0, 0);
    }

    f32x4 inv;
#pragma unroll
    for (int r = 0; r < 4; ++r) inv[r] = 1.0f / lrow[r];
#pragma unroll
    for (int dj = 0; dj < 8; ++dj) {
      f32x4 ov = o[dj] * inv;
#pragma unroll
      for (int r = 0; r < 4; ++r) {
        int q = q0 + g8 * 4 + r;
        int d = dj * 16 + c;
        O[(((size_t)b * N_L + q) * N_H + h) * N_HD + d] = (bf16)ov[r];
      }
    }
  }
}

// ---------------- launch ----------------
extern "C" void kernel_launch(void* const* d_in, const int* in_sizes, int n_in,
                              void* d_out, int out_size, void* d_ws, size_t ws_size,
                              hipStream_t stream) {
  const float* x  = (const float*)d_in[0];
  const float* wq = (const float*)d_in[1];
  const float* bq = (const float*)d_in[2];
  const float* wk = (const float*)d_in[3];
  const float* bk = (const float*)d_in[4];
  const float* wv = (const float*)d_in[5];
  const float* bv = (const float*)d_in[6];
  const float* wo = (const float*)d_in[7];
  const float* bo = (const float*)d_in[8];

  char* ws = (char*)d_ws;
  const size_t WSZ = (size_t)N_D * N_D * sizeof(bf16);    // 8 MB per transposed weight
  const size_t XSZ = (size_t)M_TOT * N_D * sizeof(bf16);  // 64 MB per activation tensor
  bf16* wqT = (bf16*)(ws);
  bf16* wkT = (bf16*)(ws + WSZ);
  bf16* wvT = (bf16*)(ws + 2 * WSZ);
  bf16* woT = (bf16*)(ws + 3 * WSZ);
  bf16* xb  = (bf16*)(ws + 4 * WSZ);
  bf16* Qb  = (bf16*)(ws + 4 * WSZ + XSZ);
  bf16* Kb  = (bf16*)(ws + 4 * WSZ + 2 * XSZ);
  bf16* Vb  = (bf16*)(ws + 4 * WSZ + 3 * XSZ);  // holds V^T: [b][h][d][l]
  bf16* Ob  = (bf16*)(ws + 4 * WSZ + 4 * XSZ);
  float2* tab = (float2*)(ws + 4 * WSZ + 5 * XSZ);

  k_cast_x<<<2048, 256, 0, stream>>>(x, xb, M_TOT * N_D / 4);
  dim3 tb(32, 32), tg(64, 64, 4);
  k_transpose_w4<<<tg, tb, 0, stream>>>(wq, wk, wv, wo, wqT, wkT, wvT, woT);
  k_trig<<<64, 256, 0, stream>>>(tab);

  const int grid = (M_TOT / 256) * (N_D / 256);  // 512
  k_gemm256<3><<<grid, 512, 0, stream>>>(xb, wqT, bq, Qb, tab);   // Q proj + RoPE
  k_gemm256<3><<<grid, 512, 0, stream>>>(xb, wkT, bk, Kb, tab);   // K proj + RoPE
  k_gemm256<2><<<grid, 512, 0, stream>>>(xb, wvT, bv, Vb, tab);   // V proj, transposed

  k_attn_mfma<<<1024, 512, 0, stream>>>(Qb, Kb, Vb, Ob);
  k_gemm256<1><<<grid, 512, 0, stream>>>(Ob, woT, bo, d_out, tab);
}